// Round 15
// baseline (193.949 us; speedup 1.0000x reference)
//
#include <hip/hip_runtime.h>
#include <hip/hip_bf16.h>
#include <stdint.h>

typedef __bf16 bf16_t;
typedef __bf16 bf16x8 __attribute__((ext_vector_type(8)));
typedef __bf16 bf16x4 __attribute__((ext_vector_type(4)));
typedef float f32x4 __attribute__((ext_vector_type(4)));
typedef float f32x16 __attribute__((ext_vector_type(16)));

#define GLD_LDS16(src, dst)                                                              \
  __builtin_amdgcn_global_load_lds((const __attribute__((address_space(1))) void*)(src), \
                                   (__attribute__((address_space(3))) void*)(dst), 16, 0, 0)

// ---------------------------------------------------------------------------
// fp32 -> bf16 convert (16B load / 8B store per lane; R11-proven).
// ---------------------------------------------------------------------------
struct CvtArgs {
  const float* src[7];
  bf16_t* dst[7];
  long n4[7];
};

__global__ __launch_bounds__(256) void cvt_all(CvtArgs a) {
  const int seg = blockIdx.y;
  const float* __restrict__ in = a.src[seg];
  bf16_t* __restrict__ out = a.dst[seg];
  const long n4 = a.n4[seg];
  long i = (long)blockIdx.x * blockDim.x + threadIdx.x;
  const long stride = (long)gridDim.x * blockDim.x;
  for (; i < n4; i += stride) {
    float4 v = ((const float4*)in)[i];
    bf16x4 o;
    o[0] = (bf16_t)v.x; o[1] = (bf16_t)v.y; o[2] = (bf16_t)v.z; o[3] = (bf16_t)v.w;
    ((bf16x4*)out)[i] = o;
  }
}

// ---------------------------------------------------------------------------
// Causal row softmax, in-place, bounded to j < (floor(i/128)+1)*128.
// ---------------------------------------------------------------------------
__global__ __launch_bounds__(256) void softmax_causal(bf16_t* __restrict__ S, int n, long sB) {
  const int i = blockIdx.x;
  const int z = blockIdx.y;
  bf16_t* row = S + (long)z * sB + (long)i * n;
  const int t = threadIdx.x;
  const int j0 = t << 3;
  const int jmax = ((i >> 7) + 1) << 7;
  const bool active = j0 < jmax;

  float vals[8];
  float mx = -3.0e38f;
  if (active) {
    bf16x8 vv = ((const bf16x8*)row)[t];
#pragma unroll
    for (int e = 0; e < 8; ++e) {
      float v = (j0 + e <= i) ? (float)vv[e] : -3.0e38f;
      vals[e] = v;
      mx = fmaxf(mx, v);
    }
  }
#pragma unroll
  for (int off = 32; off; off >>= 1) mx = fmaxf(mx, __shfl_xor(mx, off));
  __shared__ float redm[4];
  if ((t & 63) == 0) redm[t >> 6] = mx;
  __syncthreads();
  mx = fmaxf(fmaxf(redm[0], redm[1]), fmaxf(redm[2], redm[3]));

  float sum = 0.f;
  if (active) {
#pragma unroll
    for (int e = 0; e < 8; ++e) {
      float p = (j0 + e <= i) ? __expf(vals[e] - mx) : 0.f;
      vals[e] = p;
      sum += p;
    }
  }
#pragma unroll
  for (int off = 32; off; off >>= 1) sum += __shfl_xor(sum, off);
  __shared__ float reds[4];
  if ((t & 63) == 0) reds[t >> 6] = sum;
  __syncthreads();
  sum = reds[0] + reds[1] + reds[2] + reds[3];
  const float inv = 1.0f / sum;

  if (active) {
    bf16x8 o;
#pragma unroll
    for (int e = 0; e < 8; ++e) o[e] = (bf16_t)(vals[e] * inv);
    ((bf16x8*)row)[t] = o;
  }
}

// ---------------------------------------------------------------------------
// XCD-chunked bijective remap (requires nwg % 8 == 0; all grids comply).
// ---------------------------------------------------------------------------
__device__ __forceinline__ void xcd_remap(int& bx, int& by, int& bz) {
  const int gx = gridDim.x, gy = gridDim.y;
  int lin = (blockIdx.z * gy + blockIdx.y) * gx + blockIdx.x;
  const int nwg = gx * gy * (int)gridDim.z;
  lin = (lin & 7) * (nwg >> 3) + (lin >> 3);
  bx = lin % gx;
  const int rem = lin / gx;
  by = rem % gy;
  bz = rem / gy;
}

// ---------------------------------------------------------------------------
// 128 x (NS*64) GEMM core, BK=64, XOR-swizzled LDS (R10/R11-proven staging),
// now on v_mfma_f32_32x32x16_bf16 (2382 TF ubench vs 2075 for 16x16x32; half
// the MFMA instruction count). NS = 32x32 n-subfrags per wave (2 -> 128-wide
// tile / 32 KB LDS; 1 -> 64-wide / 24 KB).
// Fragment mapping: A/B row = lane&31, k = 8*(lane>>5)+j (analog of the
// verified 16x16 mapping). C/D: col=lane&31, row=(reg&3)+8*(reg>>2)+4*(l>>5).
// ---------------------------------------------------------------------------
template <int NS>
__device__ __forceinline__ void gemm_core(char* smem,
                                          const bf16_t* __restrict__ A,
                                          const bf16_t* __restrict__ B,
                                          int K, int KT, int m0, int n0,
                                          f32x16 (&acc)[2][NS]) {
  char* const asb = smem;
  char* const bsb = smem + 16384;
  const int t = threadIdx.x;
  const int l = t & 63;
  const int w = t >> 6;
  const int wr = w >> 1, wc = w & 1;
  const int l31 = l & 31, hi = l >> 5;

  // staging: chunk c -> row c>>3, phys slot c&7 holds logical (c&7)^(row&7).
  const bf16_t* a_src[4];
  const bf16_t* b_src[NS * 2];
#pragma unroll
  for (int i = 0; i < 4; ++i) {
    const int c = i * 256 + t;
    const int row = c >> 3;
    const int sl = (c & 7) ^ (row & 7);
    a_src[i] = A + (long)(m0 + row) * K + sl * 8;
  }
#pragma unroll
  for (int i = 0; i < NS * 2; ++i) {
    const int c = i * 256 + t;
    const int row = c >> 3;
    const int sl = (c & 7) ^ (row & 7);
    b_src[i] = B + (long)(n0 + row) * K + sl * 8;
  }

  // fragment read offsets: k-step kt (K=16 each), chunk = kt*2 + hi, swizzled.
  int aoff[4][2], boff[4][NS];
#pragma unroll
  for (int kt = 0; kt < 4; ++kt) {
#pragma unroll
    for (int mi = 0; mi < 2; ++mi) {
      const int ra = wr * 64 + mi * 32 + l31;
      aoff[kt][mi] = ra * 128 + ((kt * 2 + hi) ^ (ra & 7)) * 16;
    }
#pragma unroll
    for (int ni = 0; ni < NS; ++ni) {
      const int rb = wc * (NS * 32) + ni * 32 + l31;
      boff[kt][ni] = rb * 128 + ((kt * 2 + hi) ^ (rb & 7)) * 16;
    }
  }

  for (int kt = 0; kt < KT; ++kt) {
    __syncthreads();
#pragma unroll
    for (int i = 0; i < 4; ++i) {
      GLD_LDS16(a_src[i], asb + i * 4096 + w * 1024);
      a_src[i] += 64;
    }
#pragma unroll
    for (int i = 0; i < NS * 2; ++i) {
      GLD_LDS16(b_src[i], bsb + i * 4096 + w * 1024);
      b_src[i] += 64;
    }
    __syncthreads();

#pragma unroll
    for (int ks = 0; ks < 4; ++ks) {
      bf16x8 af[2], bfr[NS];
#pragma unroll
      for (int mi = 0; mi < 2; ++mi) af[mi] = *(const bf16x8*)(asb + aoff[ks][mi]);
#pragma unroll
      for (int ni = 0; ni < NS; ++ni) bfr[ni] = *(const bf16x8*)(bsb + boff[ks][ni]);
#pragma unroll
      for (int mi = 0; mi < 2; ++mi)
#pragma unroll
        for (int ni = 0; ni < NS; ++ni)
          acc[mi][ni] =
              __builtin_amdgcn_mfma_f32_32x32x16_bf16(af[mi], bfr[ni], acc[mi][ni], 0, 0, 0);
    }
  }
}

// ---------------------------------------------------------------------------
// Generic GEMM kernel: C = alpha*A[M,K]*B[N,K]^T (+bias). Tile 128 x (NS*64).
// EPI 0=fp32, 1=bf16. KBOUND: K limited to n0+NS*64 (PV causality).
// ---------------------------------------------------------------------------
template <int NS, int EPI, bool BIAS, bool KBOUND>
__global__ __launch_bounds__(256, 4) void gemm_bt(const bf16_t* __restrict__ Ag,
                                                  const bf16_t* __restrict__ Bg,
                                                  const float* __restrict__ bias,
                                                  void* __restrict__ Cout,
                                                  int N, int K, float alpha,
                                                  long sAb, long sBb, long sCb, int eltC) {
  int bx, by, bz;
  xcd_remap(bx, by, bz);
  const int m0 = by << 7, n0 = bx * (NS * 64);

  int KT = K >> 6;
  if (KBOUND) {
    const int kb = (n0 + NS * 64) >> 6;
    if (kb < KT) KT = kb;
  }

  __shared__ __align__(16) char smem[16384 + NS * 8192];
  f32x16 acc[2][NS] = {};
  gemm_core<NS>(smem, Ag + (long)bz * sAb, Bg + (long)bz * sBb, K, KT, m0, n0, acc);

  const int t = threadIdx.x;
  const int l = t & 63;
  const int w = t >> 6;
  const int wr = w >> 1, wc = w & 1;
  const int l31 = l & 31, hi = l >> 5;
  if constexpr (EPI == 0) {
    float* C = (float*)((char*)Cout + (long)bz * sCb * eltC);
#pragma unroll
    for (int mi = 0; mi < 2; ++mi)
#pragma unroll
      for (int ni = 0; ni < NS; ++ni) {
        const int col = n0 + wc * (NS * 32) + ni * 32 + l31;
        float badd = 0.f;
        if constexpr (BIAS) badd = bias[col];
#pragma unroll
        for (int g = 0; g < 4; ++g)
#pragma unroll
          for (int j = 0; j < 4; ++j) {
            const int row = m0 + wr * 64 + mi * 32 + hi * 4 + g * 8 + j;
            C[(long)row * N + col] = acc[mi][ni][g * 4 + j] * alpha + badd;
          }
      }
  } else {
    bf16_t* C = (bf16_t*)((char*)Cout + (long)bz * sCb * eltC);
#pragma unroll
    for (int mi = 0; mi < 2; ++mi)
#pragma unroll
      for (int ni = 0; ni < NS; ++ni) {
        const int col = n0 + wc * (NS * 32) + ni * 32 + l31;
        float badd = 0.f;
        if constexpr (BIAS) badd = bias[col];
#pragma unroll
        for (int g = 0; g < 4; ++g)
#pragma unroll
          for (int j = 0; j < 4; ++j) {
            const int row = m0 + wr * 64 + mi * 32 + hi * 4 + g * 8 + j;
            C[(long)row * N + col] = (bf16_t)(acc[mi][ni][g * 4 + j] * alpha + badd);
          }
      }
  }
}

// ---------------------------------------------------------------------------
// Scores: 128x64 tiles (NS=1), triangle-paired rectangular grid (17,16,4) =
// 1088 blocks, all causal-active (bijection verified R14).
// S[z] = qp[z] x kp[z]^T * (1/32).
// ---------------------------------------------------------------------------
__global__ __launch_bounds__(256, 4) void gemm_scores(const bf16_t* __restrict__ qp,
                                                      const bf16_t* __restrict__ kp,
                                                      bf16_t* __restrict__ S,
                                                      long nd, long nn) {
  int bx, by, bz;
  xcd_remap(bx, by, bz);
  int r, c;
  if (bx <= 2 * by + 1) { r = by; c = bx; }
  else { r = 15 - by; c = bx + 15 - 2 * by; }
  const int m0 = r << 7, n0 = c << 6;

  __shared__ __align__(16) char smem[24576];
  f32x16 acc[2][1] = {};
  gemm_core<1>(smem, qp + (long)bz * nd, kp + (long)bz * nd, 1024, 16, m0, n0, acc);

  const int t = threadIdx.x;
  const int l = t & 63;
  const int w = t >> 6;
  const int wr = w >> 1, wc = w & 1;
  const int l31 = l & 31, hi = l >> 5;
  bf16_t* C = S + (long)bz * nn;
#pragma unroll
  for (int mi = 0; mi < 2; ++mi) {
    const int col = n0 + wc * 32 + l31;
#pragma unroll
    for (int g = 0; g < 4; ++g)
#pragma unroll
      for (int j = 0; j < 4; ++j) {
        const int row = m0 + wr * 64 + mi * 32 + hi * 4 + g * 8 + j;
        C[(long)row * 2048 + col] = (bf16_t)(acc[mi][0][g * 4 + j] * 0.03125f);
      }
  }
}

// ---------------------------------------------------------------------------
// Fused QKV projections (NS=2 core). z<2: normal store; z==2: V transposed
// into vpT via chunk-XOR-swizzled LDS transpose (R11-proven readback).
// ---------------------------------------------------------------------------
struct Qkv3Args {
  const bf16_t* A[3];
  const bf16_t* W[3];
  const float* bias[3];
  bf16_t* C[3];
};

__global__ __launch_bounds__(256, 4) void qkv3(Qkv3Args ga, int N, int K) {
  int bx, by, bz;
  xcd_remap(bx, by, bz);
  const int m0 = by << 7, n0 = bx << 7;

  __shared__ __align__(16) char smem[32768];
  f32x16 acc[2][2] = {};
  gemm_core<2>(smem, ga.A[bz], ga.W[bz], K, K >> 6, m0, n0, acc);

  const float* __restrict__ bias = ga.bias[bz];
  const int t = threadIdx.x;
  const int l = t & 63;
  const int w = t >> 6;
  const int wr = w >> 1, wc = w & 1;
  const int l31 = l & 31, hi = l >> 5;

  if (bz < 2) {
    bf16_t* C = ga.C[bz];
#pragma unroll
    for (int mi = 0; mi < 2; ++mi)
#pragma unroll
      for (int ni = 0; ni < 2; ++ni) {
        const int col = n0 + wc * 64 + ni * 32 + l31;
        const float badd = bias[col];
#pragma unroll
        for (int g = 0; g < 4; ++g)
#pragma unroll
          for (int j = 0; j < 4; ++j) {
            const int row = m0 + wr * 64 + mi * 32 + hi * 4 + g * 8 + j;
            C[(long)row * N + col] = (bf16_t)(acc[mi][ni][g * 4 + j] + badd);
          }
      }
  } else {
    // transpose in LDS (chunk-XOR swizzled), then coalesced 16B stores along n
    __syncthreads();  // K-loop LDS reads complete before overwrite
    char* tt = smem;  // [128 rows(d)][256 B], phys chunk = logical^(lc&7)
#pragma unroll
    for (int mi = 0; mi < 2; ++mi)
#pragma unroll
      for (int ni = 0; ni < 2; ++ni) {
        const int lc = wc * 64 + ni * 32 + l31;  // local d-col
        const float badd = bias[n0 + lc];
#pragma unroll
        for (int g = 0; g < 4; ++g) {
          const int lr = wr * 64 + mi * 32 + hi * 4 + g * 8;  // local n-row (4 consecutive)
          const int lrb = lr * 2;
          bf16x4 o;
#pragma unroll
          for (int j = 0; j < 4; ++j) o[j] = (bf16_t)(acc[mi][ni][g * 4 + j] + badd);
          *(bf16x4*)(tt + lc * 256 + (lrb ^ ((lc & 7) << 4))) = o;
        }
      }
    __syncthreads();
    bf16_t* C = ga.C[2];
    const int batch = m0 >> 11, nb = m0 & 2047;
#pragma unroll
    for (int i = 0; i < 8; ++i) {
      const int c = i * 256 + t;
      const int lc = c >> 4, ch = c & 15;
      *(bf16x8*)(C + (long)batch * (2048 * 1024) + (long)(n0 + lc) * 2048 + nb + ch * 8) =
          *(const bf16x8*)(tt + lc * 256 + ((ch * 16) ^ ((lc & 7) << 4)));
    }
  }
}

// ---------------------------------------------------------------------------
extern "C" void kernel_launch(void* const* d_in, const int* in_sizes, int n_in,
                              void* d_out, int out_size, void* d_ws, size_t ws_size,
                              hipStream_t stream) {
  const int b = 4, n = 2048, d = 1024;
  const long nd  = (long)n * d;
  const long bn  = (long)b * n;
  const long bnd = bn * d;
  const long ddl = (long)d * d;
  const long nn  = (long)n * n;

  const float* q  = (const float*)d_in[0];
  const float* k  = (const float*)d_in[1];
  const float* v  = (const float*)d_in[2];
  const float* Wq = (const float*)d_in[3];
  const float* bq = (const float*)d_in[4];
  const float* Wk = (const float*)d_in[5];
  const float* bk = (const float*)d_in[6];
  const float* Wv = (const float*)d_in[7];
  const float* bv = (const float*)d_in[8];
  const float* Wo = (const float*)d_in[9];
  const float* bo = (const float*)d_in[10];

  bf16_t* ws  = (bf16_t*)d_ws;
  bf16_t* qB  = ws;
  bf16_t* kB  = qB + bnd;
  bf16_t* vB  = kB + bnd;
  bf16_t* WqB = vB + bnd;
  bf16_t* WkB = WqB + ddl;
  bf16_t* WvB = WkB + ddl;
  bf16_t* WoB = WvB + ddl;
  bf16_t* qpB = WoB + ddl;
  bf16_t* kpB = qpB + bnd;
  bf16_t* vpT = kpB + bnd;
  bf16_t* S   = vpT + bnd;
  bf16_t* yT  = S + (long)b * nn;
  const size_t need = (size_t)(7 * bnd + 4 * ddl + (long)b * nn) * 2;
  if (ws_size < need) return;

  dim3 blk(256);

  // fp32 -> bf16 converts
  CvtArgs ca;
  ca.src[0] = q;  ca.dst[0] = qB;  ca.n4[0] = bnd / 4;
  ca.src[1] = k;  ca.dst[1] = kB;  ca.n4[1] = bnd / 4;
  ca.src[2] = v;  ca.dst[2] = vB;  ca.n4[2] = bnd / 4;
  ca.src[3] = Wq; ca.dst[3] = WqB; ca.n4[3] = ddl / 4;
  ca.src[4] = Wk; ca.dst[4] = WkB; ca.n4[4] = ddl / 4;
  ca.src[5] = Wv; ca.dst[5] = WvB; ca.n4[5] = ddl / 4;
  ca.src[6] = Wo; ca.dst[6] = WoB; ca.n4[6] = ddl / 4;
  cvt_all<<<dim3(512, 7), blk, 0, stream>>>(ca);

  // fused QKV projections: grid (8, 64, 3) = 1536 blocks
  Qkv3Args qa;
  qa.A[0] = qB; qa.W[0] = WqB; qa.bias[0] = bq; qa.C[0] = qpB;
  qa.A[1] = kB; qa.W[1] = WkB; qa.bias[1] = bk; qa.C[1] = kpB;
  qa.A[2] = vB; qa.W[2] = WvB; qa.bias[2] = bv; qa.C[2] = vpT;
  qkv3<<<dim3(d / 128, bn / 128, 3), blk, 0, stream>>>(qa, d, d);

  // scores: 128x64 tiles, triangle-paired grid (17,16,4) = 1088 blocks
  gemm_scores<<<dim3(17, 16, b), blk, 0, stream>>>(qpB, kpB, S, nd, nn);

  // causal softmax in place (bounded)
  softmax_causal<<<dim3(n, b), blk, 0, stream>>>(S, n, nn);

  // yT[z] = vpT[z] x P[z]^T, 128x64 tiles: grid (32, 8, 4) = 1024 blocks
  gemm_bt<1, 1, false, true><<<dim3(n / 64, d / 128, b), blk, 0, stream>>>(
      vpT, S, nullptr, yT, n, n, 1.f, nd, nn, nd, 2);

  // out = y2 x Wo^T + bo, 128x64 tiles: grid (16, 64, 1) = 1024 blocks
  gemm_bt<1, 0, true, false><<<dim3(d / 64, bn / 128, 1), blk, 0, stream>>>(
      yT, WoB, bo, (float*)d_out, d, d, 1.f, 0, 0, 0, 4);
}

// Round 16
// 181.379 us; speedup vs baseline: 1.0693x; 1.0693x over previous
//
#include <hip/hip_runtime.h>
#include <hip/hip_bf16.h>
#include <stdint.h>

typedef __bf16 bf16_t;
typedef __bf16 bf16x8 __attribute__((ext_vector_type(8)));
typedef __bf16 bf16x4 __attribute__((ext_vector_type(4)));
typedef float f32x4 __attribute__((ext_vector_type(4)));

#define GLD_LDS16(src, dst)                                                              \
  __builtin_amdgcn_global_load_lds((const __attribute__((address_space(1))) void*)(src), \
                                   (__attribute__((address_space(3))) void*)(dst), 16, 0, 0)

// ---------------------------------------------------------------------------
// fp32 -> bf16 convert (16B load / 8B store per lane; R11-proven).
// ---------------------------------------------------------------------------
struct CvtArgs {
  const float* src[7];
  bf16_t* dst[7];
  long n4[7];
};

__global__ __launch_bounds__(256) void cvt_all(CvtArgs a) {
  const int seg = blockIdx.y;
  const float* __restrict__ in = a.src[seg];
  bf16_t* __restrict__ out = a.dst[seg];
  const long n4 = a.n4[seg];
  long i = (long)blockIdx.x * blockDim.x + threadIdx.x;
  const long stride = (long)gridDim.x * blockDim.x;
  for (; i < n4; i += stride) {
    float4 v = ((const float4*)in)[i];
    bf16x4 o;
    o[0] = (bf16_t)v.x; o[1] = (bf16_t)v.y; o[2] = (bf16_t)v.z; o[3] = (bf16_t)v.w;
    ((bf16x4*)out)[i] = o;
  }
}

// ---------------------------------------------------------------------------
// Causal row softmax, in-place, bounded to j < (floor(i/128)+1)*128.
// ---------------------------------------------------------------------------
__global__ __launch_bounds__(256) void softmax_causal(bf16_t* __restrict__ S, int n, long sB) {
  const int i = blockIdx.x;
  const int z = blockIdx.y;
  bf16_t* row = S + (long)z * sB + (long)i * n;
  const int t = threadIdx.x;
  const int j0 = t << 3;
  const int jmax = ((i >> 7) + 1) << 7;
  const bool active = j0 < jmax;

  float vals[8];
  float mx = -3.0e38f;
  if (active) {
    bf16x8 vv = ((const bf16x8*)row)[t];
#pragma unroll
    for (int e = 0; e < 8; ++e) {
      float v = (j0 + e <= i) ? (float)vv[e] : -3.0e38f;
      vals[e] = v;
      mx = fmaxf(mx, v);
    }
  }
#pragma unroll
  for (int off = 32; off; off >>= 1) mx = fmaxf(mx, __shfl_xor(mx, off));
  __shared__ float redm[4];
  if ((t & 63) == 0) redm[t >> 6] = mx;
  __syncthreads();
  mx = fmaxf(fmaxf(redm[0], redm[1]), fmaxf(redm[2], redm[3]));

  float sum = 0.f;
  if (active) {
#pragma unroll
    for (int e = 0; e < 8; ++e) {
      float p = (j0 + e <= i) ? __expf(vals[e] - mx) : 0.f;
      vals[e] = p;
      sum += p;
    }
  }
#pragma unroll
  for (int off = 32; off; off >>= 1) sum += __shfl_xor(sum, off);
  __shared__ float reds[4];
  if ((t & 63) == 0) reds[t >> 6] = sum;
  __syncthreads();
  sum = reds[0] + reds[1] + reds[2] + reds[3];
  const float inv = 1.0f / sum;

  if (active) {
    bf16x8 o;
#pragma unroll
    for (int e = 0; e < 8; ++e) o[e] = (bf16_t)(vals[e] * inv);
    ((bf16x8*)row)[t] = o;
  }
}

// ---------------------------------------------------------------------------
// XCD-chunked bijective remap (requires nwg % 8 == 0; all grids comply).
// ---------------------------------------------------------------------------
__device__ __forceinline__ void xcd_remap(int& bx, int& by, int& bz) {
  const int gx = gridDim.x, gy = gridDim.y;
  int lin = (blockIdx.z * gy + blockIdx.y) * gx + blockIdx.x;
  const int nwg = gx * gy * (int)gridDim.z;
  lin = (lin & 7) * (nwg >> 3) + (lin >> 3);
  bx = lin % gx;
  const int rem = lin / gx;
  by = rem % gy;
  bz = rem / gy;
}

// ---------------------------------------------------------------------------
// 128 x (NF*32) GEMM core, BK=64, two inner k-passes (32 MFMA per barrier
// pair), XOR-swizzled LDS (T2, both-sides; verified conflict-free: 131K).
// NF=4 -> 128-wide (32 KB LDS), NF=2 -> 64-wide (24 KB LDS).
// 16x16x32 MFMA: same matrix-pipe cycles as 32x32x16 (R15 A/B) but better
// ILP against ds_reads and a conflict-free epilogue swizzle.
// ---------------------------------------------------------------------------
template <int NF>
__device__ __forceinline__ void gemm_core(char* smem,
                                          const bf16_t* __restrict__ A,
                                          const bf16_t* __restrict__ B,
                                          int K, int KT, int m0, int n0,
                                          f32x4 (&acc)[4][NF]) {
  char* const asb = smem;
  char* const bsb = smem + 16384;
  const int t = threadIdx.x;
  const int l = t & 63;
  const int w = t >> 6;
  const int wr = w >> 1, wc = w & 1;
  const int r16 = l & 15, kg = l >> 4;

  const bf16_t* a_src[4];
  const bf16_t* b_src[NF];
#pragma unroll
  for (int i = 0; i < 4; ++i) {
    const int c = i * 256 + t;
    const int row = c >> 3;
    const int sl = (c & 7) ^ (row & 7);
    a_src[i] = A + (long)(m0 + row) * K + sl * 8;
  }
#pragma unroll
  for (int i = 0; i < NF; ++i) {
    const int c = i * 256 + t;
    const int row = c >> 3;
    const int sl = (c & 7) ^ (row & 7);
    b_src[i] = B + (long)(n0 + row) * K + sl * 8;
  }

  int aoff[2][4], boff[2][NF];
#pragma unroll
  for (int kp = 0; kp < 2; ++kp) {
#pragma unroll
    for (int mi = 0; mi < 4; ++mi) {
      const int ra = wr * 64 + mi * 16 + r16;
      aoff[kp][mi] = ra * 128 + ((kp * 4 + kg) ^ (ra & 7)) * 16;
    }
#pragma unroll
    for (int ni = 0; ni < NF; ++ni) {
      const int rb = wc * (NF * 16) + ni * 16 + r16;
      boff[kp][ni] = rb * 128 + ((kp * 4 + kg) ^ (rb & 7)) * 16;
    }
  }

  for (int kt = 0; kt < KT; ++kt) {
    __syncthreads();
#pragma unroll
    for (int i = 0; i < 4; ++i) {
      GLD_LDS16(a_src[i], asb + i * 4096 + w * 1024);
      a_src[i] += 64;
    }
#pragma unroll
    for (int i = 0; i < NF; ++i) {
      GLD_LDS16(b_src[i], bsb + i * 4096 + w * 1024);
      b_src[i] += 64;
    }
    __syncthreads();

#pragma unroll
    for (int kp = 0; kp < 2; ++kp) {
      bf16x8 af[4], bfr[NF];
#pragma unroll
      for (int mi = 0; mi < 4; ++mi) af[mi] = *(const bf16x8*)(asb + aoff[kp][mi]);
#pragma unroll
      for (int ni = 0; ni < NF; ++ni) bfr[ni] = *(const bf16x8*)(bsb + boff[kp][ni]);
#pragma unroll
      for (int mi = 0; mi < 4; ++mi)
#pragma unroll
        for (int ni = 0; ni < NF; ++ni)
          acc[mi][ni] =
              __builtin_amdgcn_mfma_f32_16x16x32_bf16(af[mi], bfr[ni], acc[mi][ni], 0, 0, 0);
    }
  }
}

// ---------------------------------------------------------------------------
// Generic GEMM kernel: C = alpha*A[M,K]*B[N,K]^T (+bias). Tile 128 x (NF*32).
// EPI 0=fp32, 1=bf16. KBOUND: K limited to n0+NF*32 (PV causality).
// ---------------------------------------------------------------------------
template <int NF, int EPI, bool BIAS, bool KBOUND>
__global__ __launch_bounds__(256, 4) void gemm_bt(const bf16_t* __restrict__ Ag,
                                                  const bf16_t* __restrict__ Bg,
                                                  const float* __restrict__ bias,
                                                  void* __restrict__ Cout,
                                                  int N, int K, float alpha,
                                                  long sAb, long sBb, long sCb, int eltC) {
  int bx, by, bz;
  xcd_remap(bx, by, bz);
  const int m0 = by << 7, n0 = bx * (NF * 32);

  int KT = K >> 6;
  if (KBOUND) {
    const int kb = (n0 + NF * 32) >> 6;
    if (kb < KT) KT = kb;
  }

  __shared__ __align__(16) char smem[16384 + NF * 4096];
  f32x4 acc[4][NF] = {};
  gemm_core<NF>(smem, Ag + (long)bz * sAb, Bg + (long)bz * sBb, K, KT, m0, n0, acc);

  const int t = threadIdx.x;
  const int l = t & 63;
  const int w = t >> 6;
  const int wr = w >> 1, wc = w & 1;
  const int rowbase = m0 + wr * 64 + ((l >> 4) << 2);
  const int colbase = n0 + wc * (NF * 16) + (l & 15);
  if constexpr (EPI == 0) {
    float* C = (float*)((char*)Cout + (long)bz * sCb * eltC);
#pragma unroll
    for (int mi = 0; mi < 4; ++mi)
#pragma unroll
      for (int ni = 0; ni < NF; ++ni) {
        const int col = colbase + ni * 16;
        float badd = 0.f;
        if constexpr (BIAS) badd = bias[col];
#pragma unroll
        for (int j = 0; j < 4; ++j)
          C[(long)(rowbase + mi * 16 + j) * N + col] = acc[mi][ni][j] * alpha + badd;
      }
  } else {
    bf16_t* C = (bf16_t*)((char*)Cout + (long)bz * sCb * eltC);
#pragma unroll
    for (int mi = 0; mi < 4; ++mi)
#pragma unroll
      for (int ni = 0; ni < NF; ++ni) {
        const int col = colbase + ni * 16;
        float badd = 0.f;
        if constexpr (BIAS) badd = bias[col];
#pragma unroll
        for (int j = 0; j < 4; ++j)
          C[(long)(rowbase + mi * 16 + j) * N + col] = (bf16_t)(acc[mi][ni][j] * alpha + badd);
      }
  }
}

// ---------------------------------------------------------------------------
// Scores: 128x64 tiles, triangle-paired rectangular grid (17,16,4) = 1088
// blocks, all causal-active (bijection verified R14).
// S[z] = qp[z] x kp[z]^T * (1/32).
// ---------------------------------------------------------------------------
__global__ __launch_bounds__(256, 4) void gemm_scores(const bf16_t* __restrict__ qp,
                                                      const bf16_t* __restrict__ kp,
                                                      bf16_t* __restrict__ S,
                                                      long nd, long nn) {
  int bx, by, bz;
  xcd_remap(bx, by, bz);
  int r, c;
  if (bx <= 2 * by + 1) { r = by; c = bx; }
  else { r = 15 - by; c = bx + 15 - 2 * by; }
  const int m0 = r << 7, n0 = c << 6;

  __shared__ __align__(16) char smem[24576];
  f32x4 acc[4][2] = {};
  gemm_core<2>(smem, qp + (long)bz * nd, kp + (long)bz * nd, 1024, 16, m0, n0, acc);

  const int t = threadIdx.x;
  const int l = t & 63;
  const int w = t >> 6;
  const int wr = w >> 1, wc = w & 1;
  const int rowbase = m0 + wr * 64 + ((l >> 4) << 2);
  const int colbase = n0 + wc * 32 + (l & 15);
  bf16_t* C = S + (long)bz * nn;
#pragma unroll
  for (int mi = 0; mi < 4; ++mi)
#pragma unroll
    for (int ni = 0; ni < 2; ++ni) {
      const int col = colbase + ni * 16;
#pragma unroll
      for (int j = 0; j < 4; ++j)
        C[(long)(rowbase + mi * 16 + j) * 2048 + col] = (bf16_t)(acc[mi][ni][j] * 0.03125f);
    }
}

// ---------------------------------------------------------------------------
// Fused QKV projections (128x128 core). z<2: normal store; z==2: V transposed
// into vpT via chunk-XOR-swizzled LDS transpose (conflicts 131K, verified).
// ---------------------------------------------------------------------------
struct Qkv3Args {
  const bf16_t* A[3];
  const bf16_t* W[3];
  const float* bias[3];
  bf16_t* C[3];
};

__global__ __launch_bounds__(256, 4) void qkv3(Qkv3Args ga, int N, int K) {
  int bx, by, bz;
  xcd_remap(bx, by, bz);
  const int m0 = by << 7, n0 = bx << 7;

  __shared__ __align__(16) char smem[32768];
  f32x4 acc[4][4] = {};
  gemm_core<4>(smem, ga.A[bz], ga.W[bz], K, K >> 6, m0, n0, acc);

  const float* __restrict__ bias = ga.bias[bz];
  const int t = threadIdx.x;
  const int l = t & 63;
  const int w = t >> 6;
  const int wr = w >> 1, wc = w & 1;
  const int r16 = l & 15, kg = l >> 4;

  if (bz < 2) {
    bf16_t* C = ga.C[bz];
    const int rowbase = m0 + wr * 64 + kg * 4;
    const int colbase = n0 + wc * 64 + r16;
#pragma unroll
    for (int mi = 0; mi < 4; ++mi)
#pragma unroll
      for (int ni = 0; ni < 4; ++ni) {
        const int col = colbase + ni * 16;
        const float badd = bias[col];
#pragma unroll
        for (int j = 0; j < 4; ++j)
          C[(long)(rowbase + mi * 16 + j) * N + col] = (bf16_t)(acc[mi][ni][j] + badd);
      }
  } else {
    __syncthreads();
    char* tt = smem;  // [128 rows(d)][256 B], phys chunk = logical^(lc&7)
#pragma unroll
    for (int mi = 0; mi < 4; ++mi)
#pragma unroll
      for (int ni = 0; ni < 4; ++ni) {
        const int lc = wc * 64 + ni * 16 + r16;
        const int lrb = (wr * 64 + mi * 16 + kg * 4) * 2;
        const float badd = bias[n0 + lc];
        bf16x4 o;
#pragma unroll
        for (int j = 0; j < 4; ++j) o[j] = (bf16_t)(acc[mi][ni][j] + badd);
        *(bf16x4*)(tt + lc * 256 + (lrb ^ ((lc & 7) << 4))) = o;
      }
    __syncthreads();
    bf16_t* C = ga.C[2];
    const int batch = m0 >> 11, nb = m0 & 2047;
#pragma unroll
    for (int i = 0; i < 8; ++i) {
      const int c = i * 256 + t;
      const int lc = c >> 4, ch = c & 15;
      *(bf16x8*)(C + (long)batch * (2048 * 1024) + (long)(n0 + lc) * 2048 + nb + ch * 8) =
          *(const bf16x8*)(tt + lc * 256 + ((ch * 16) ^ ((lc & 7) << 4)));
    }
  }
}

// ---------------------------------------------------------------------------
extern "C" void kernel_launch(void* const* d_in, const int* in_sizes, int n_in,
                              void* d_out, int out_size, void* d_ws, size_t ws_size,
                              hipStream_t stream) {
  const int b = 4, n = 2048, d = 1024;
  const long nd  = (long)n * d;
  const long bn  = (long)b * n;
  const long bnd = bn * d;
  const long ddl = (long)d * d;
  const long nn  = (long)n * n;

  const float* q  = (const float*)d_in[0];
  const float* k  = (const float*)d_in[1];
  const float* v  = (const float*)d_in[2];
  const float* Wq = (const float*)d_in[3];
  const float* bq = (const float*)d_in[4];
  const float* Wk = (const float*)d_in[5];
  const float* bk = (const float*)d_in[6];
  const float* Wv = (const float*)d_in[7];
  const float* bv = (const float*)d_in[8];
  const float* Wo = (const float*)d_in[9];
  const float* bo = (const float*)d_in[10];

  bf16_t* ws  = (bf16_t*)d_ws;
  bf16_t* qB  = ws;
  bf16_t* kB  = qB + bnd;
  bf16_t* vB  = kB + bnd;
  bf16_t* WqB = vB + bnd;
  bf16_t* WkB = WqB + ddl;
  bf16_t* WvB = WkB + ddl;
  bf16_t* WoB = WvB + ddl;
  bf16_t* qpB = WoB + ddl;
  bf16_t* kpB = qpB + bnd;
  bf16_t* vpT = kpB + bnd;
  bf16_t* S   = vpT + bnd;
  bf16_t* yT  = S + (long)b * nn;
  const size_t need = (size_t)(7 * bnd + 4 * ddl + (long)b * nn) * 2;
  if (ws_size < need) return;

  dim3 blk(256);

  // fp32 -> bf16 converts
  CvtArgs ca;
  ca.src[0] = q;  ca.dst[0] = qB;  ca.n4[0] = bnd / 4;
  ca.src[1] = k;  ca.dst[1] = kB;  ca.n4[1] = bnd / 4;
  ca.src[2] = v;  ca.dst[2] = vB;  ca.n4[2] = bnd / 4;
  ca.src[3] = Wq; ca.dst[3] = WqB; ca.n4[3] = ddl / 4;
  ca.src[4] = Wk; ca.dst[4] = WkB; ca.n4[4] = ddl / 4;
  ca.src[5] = Wv; ca.dst[5] = WvB; ca.n4[5] = ddl / 4;
  ca.src[6] = Wo; ca.dst[6] = WoB; ca.n4[6] = ddl / 4;
  cvt_all<<<dim3(512, 7), blk, 0, stream>>>(ca);

  // fused QKV projections: grid (8, 64, 3) = 1536 blocks
  Qkv3Args qa;
  qa.A[0] = qB; qa.W[0] = WqB; qa.bias[0] = bq; qa.C[0] = qpB;
  qa.A[1] = kB; qa.W[1] = WkB; qa.bias[1] = bk; qa.C[1] = kpB;
  qa.A[2] = vB; qa.W[2] = WvB; qa.bias[2] = bv; qa.C[2] = vpT;
  qkv3<<<dim3(d / 128, bn / 128, 3), blk, 0, stream>>>(qa, d, d);

  // scores: 128x64 tiles, triangle-paired grid (17,16,4) = 1088 blocks
  gemm_scores<<<dim3(17, 16, b), blk, 0, stream>>>(qpB, kpB, S, nd, nn);

  // causal softmax in place (bounded)
  softmax_causal<<<dim3(n, b), blk, 0, stream>>>(S, n, nn);

  // yT[z] = vpT[z] x P[z]^T, 128x64 tiles: grid (32, 8, 4) = 1024 blocks
  gemm_bt<2, 1, false, true><<<dim3(n / 64, d / 128, b), blk, 0, stream>>>(
      vpT, S, nullptr, yT, n, n, 1.f, nd, nn, nd, 2);

  // out = y2 x Wo^T + bo, 128x64 tiles: grid (16, 64, 1) = 1024 blocks
  gemm_bt<2, 0, true, false><<<dim3(d / 64, bn / 128, 1), blk, 0, stream>>>(
      yT, WoB, bo, (float*)d_out, d, d, 1.f, 0, 0, 0, 4);
}